// Round 1
// 512.376 us; speedup vs baseline: 1.0443x; 1.0443x over previous
//
#include <hip/hip_runtime.h>

// Problem constants
#define N4 4096
#define FF 32
#define KK 6
#define OO 128
#define BB 4

typedef __attribute__((ext_vector_type(8))) short  short8;   // 8 bf16 MFMA A/B frag
typedef __attribute__((ext_vector_type(4))) float  f32x4;
typedef __attribute__((ext_vector_type(4))) int    i32x4;
typedef __attribute__((ext_vector_type(2))) unsigned int u32x2;

__device__ __forceinline__ float b2f(unsigned short h) {
    union { float f; unsigned u; } v; v.u = ((unsigned)h) << 16; return v.f;
}
__device__ __forceinline__ unsigned short f2b(float f) {
    union { float f; unsigned u; } v; v.f = f;
    unsigned r = (v.u + 0x7FFFu + ((v.u >> 16) & 1u)) >> 16;
    return (unsigned short)r;
}

// Tb frag layout: element (f, n) of T lives at
//   tb_idx(b, ks=n>>5, half=f>>4, lane=((n>>3)&3)*16 + (f&15)) + (n&7)
__device__ __forceinline__ long tb_idx(int b, int ks, int half, int lane) {
    return ((((long)b * 128 + ks) * 2 + half) * 64 + lane) * 8;
}

// ---------------------------------------------------------------------------
// Wc[k][f][o] = bf16(theta[k] * W[k][f][o])
__global__ __launch_bounds__(256) void make_wc(const float* __restrict__ W,
                                               const float* __restrict__ theta,
                                               unsigned short* __restrict__ Wc) {
    int idx = blockIdx.x * 256 + threadIdx.x;
    int k = idx >> 12;
    Wc[idx] = f2b(theta[k] * W[idx]);
}

// ---------------------------------------------------------------------------
// x [B][N][F] f32 -> T0 in Tb frag layout.  grid B*64=256 blocks (b, nc).
__global__ __launch_bounds__(256) void x_to_t(const float* __restrict__ x,
                                              unsigned short* __restrict__ T0) {
    __shared__ __align__(16) unsigned short Ol[32][72];   // [f][n-local]
    int tid = threadIdx.x, bid = blockIdx.x;
    int b = bid >> 6; int nc = bid & 63; long n0 = (long)nc * 64;
    int nl = tid >> 2, fg = (tid & 3) * 8;
    const float* src = x + ((long)b * N4 + n0 + nl) * FF + fg;
    f32x4 v0 = *(const f32x4*)src;
    f32x4 v1 = *(const f32x4*)(src + 4);
#pragma unroll
    for (int e = 0; e < 4; ++e) {
        Ol[fg + e][nl]     = f2b(v0[e]);
        Ol[fg + 4 + e][nl] = f2b(v1[e]);
    }
    __syncthreads();
    int ks_l = tid >> 7, half = (tid >> 6) & 1, lane = tid & 63;
    int quad = lane >> 4, l16 = lane & 15;
    int f = half * 16 + l16, nloc = ks_l * 32 + quad * 8;
    *(i32x4*)(T0 + tb_idx(b, nc * 2 + ks_l, half, lane)) = *(const i32x4*)&Ol[f][nloc];
}

// ---------------------------------------------------------------------------
// Fused split-k reduce + Chebyshev update + Tb-layout store.
// Block (b, ms) covers output rows n = ms*16 .. ms*16+15.
// Pr[s][h][lane][r] holds the 4 waves' D-frags:
//   f = h*16 + (lane&15), n_local = (lane>>4)*4 + r.
// T_out(f, n) = a * sum_s Pr + c * T_prev(f, n), written as Tb frags.
__device__ __forceinline__ void split_reduce_store(const float (*Pr)[2][64][4],
                                                   int tid, int b, int ms,
                                                   const unsigned short* __restrict__ Tpp,
                                                   unsigned short* __restrict__ Tout,
                                                   float a, float c) {
    if (tid >= 64) return;
    int half = tid >> 5, qi = (tid >> 4) & 1, l16 = tid & 15;
    // n_local = qi*8 + p; p 0..3 come from quad 2*qi (sA), p 4..7 from quad 2*qi+1 (sB)
    f32x4 sA = {0.f, 0.f, 0.f, 0.f}, sB = {0.f, 0.f, 0.f, 0.f};
#pragma unroll
    for (int ss = 0; ss < 4; ++ss) {
        f32x4 va = *(const f32x4*)&Pr[ss][half][qi * 32 + l16][0];
        f32x4 vb = *(const f32x4*)&Pr[ss][half][qi * 32 + 16 + l16][0];
#pragma unroll
        for (int e = 0; e < 4; ++e) { sA[e] += va[e]; sB[e] += vb[e]; }
    }
    float vals[8] = {sA[0], sA[1], sA[2], sA[3], sB[0], sB[1], sB[2], sB[3]};
    int lane_o = ((ms & 1) * 2 + qi) * 16 + l16;
    long oidx = tb_idx(b, ms >> 1, half, lane_o);
    i32x4 pk;
    if (Tpp) {
        short8 tv = *(const short8*)(Tpp + oidx);
#pragma unroll
        for (int p = 0; p < 4; ++p)
            pk[p] = (unsigned)f2b(a * vals[2 * p]     + c * b2f((unsigned short)tv[2 * p]))
                  | ((unsigned)f2b(a * vals[2 * p + 1] + c * b2f((unsigned short)tv[2 * p + 1])) << 16);
    } else {
#pragma unroll
        for (int p = 0; p < 4; ++p)
            pk[p] = (unsigned)f2b(a * vals[2 * p])
                  | ((unsigned)f2b(a * vals[2 * p + 1]) << 16);
    }
    *(i32x4*)(Tout + oidx) = pk;
}

// ---------------------------------------------------------------------------
// Pass 1 fused: reads f32 L (coalesced 256B/row chunks), wave-local LDS permute
// to frag layout, writes Lb (wave-contiguous 1KB), computes T1 = L @ T0, and
// reduces split-k in-block -> writes T1 directly (no P round-trip).
// grid 1024 blocks (b, ms) x 4 waves (w = split-k quarter).
__global__ __launch_bounds__(256) void gemm_pass1(const float* __restrict__ L,
                                                  unsigned short* __restrict__ Lb,
                                                  const unsigned short* __restrict__ Tb0,
                                                  unsigned short* __restrict__ Tout) {
    __shared__ __align__(16) unsigned short Sw[4][2][2][64][8];  // [wave][buf][ks_loc][lane][e]
    __shared__ __align__(16) float Pr[4][2][64][4];              // split-k partials
    int tid = threadIdx.x, bid = blockIdx.x;
    int b = bid >> 8, ms = bid & 255;
    int w = tid >> 6, lane = tid & 63, l16 = lane & 15;
    int rgrp = lane >> 4;                       // row group for reads
    // read: instr j covers rows j*4+rgrp, k chunk l16*4 (256B contiguous/row)
    const float* Ls = L + ((long)b * N4 + ms * 16 + rgrp) * N4 + (long)w * 1024 + l16 * 4;
    int ks_loc_w = l16 >> 3, quad_w = (l16 >> 1) & 3, e0 = (l16 & 1) * 4;
    const unsigned short* Bbase = Tb0 + tb_idx(b, w * 32, 0, lane);
    unsigned short* LbBase = Lb + (((long)(b * 256 + ms) * 128 + w * 32) * 64 + lane) * 8;

    f32x4 acc0 = {0.f,0.f,0.f,0.f}, acc1 = {0.f,0.f,0.f,0.f};
    f32x4 v[4], vn[4];
#pragma unroll
    for (int j = 0; j < 4; ++j) v[j] = *(const f32x4*)(Ls + (long)j * 4 * N4);

    for (int it = 0; it < 16; ++it) {
        if (it + 1 < 16) {
#pragma unroll
            for (int j = 0; j < 4; ++j)
                vn[j] = *(const f32x4*)(Ls + (long)j * 4 * N4 + (it + 1) * 64);
        }
        // B frags for the two ks of this iteration (L2-hot, wave-contiguous)
        short8 b00 = *(const short8*)(Bbase + (long)(it * 2 + 0) * 1024);
        short8 b01 = *(const short8*)(Bbase + (long)(it * 2 + 0) * 1024 + 512);
        short8 b10 = *(const short8*)(Bbase + (long)(it * 2 + 1) * 1024);
        short8 b11 = *(const short8*)(Bbase + (long)(it * 2 + 1) * 1024 + 512);
        // convert + LDS permute (wave-local, double-buffered)
        unsigned short* Sb = &Sw[w][it & 1][0][0][0];
#pragma unroll
        for (int j = 0; j < 4; ++j) {
            u32x2 pk;
            pk[0] = (unsigned)f2b(v[j][0]) | ((unsigned)f2b(v[j][1]) << 16);
            pk[1] = (unsigned)f2b(v[j][2]) | ((unsigned)f2b(v[j][3]) << 16);
            int lane_o = quad_w * 16 + j * 4 + rgrp;
            *(u32x2*)(Sb + (ks_loc_w * 64 + lane_o) * 8 + e0) = pk;
        }
#pragma unroll
        for (int h = 0; h < 2; ++h) {
            short8 af = *(const short8*)(Sb + (h * 64 + lane) * 8);
            *(short8*)(LbBase + (long)(it * 2 + h) * 512) = af;  // 1KB wave-contiguous
            acc0 = __builtin_amdgcn_mfma_f32_16x16x32_bf16(af, h ? b10 : b00, acc0, 0, 0, 0);
            acc1 = __builtin_amdgcn_mfma_f32_16x16x32_bf16(af, h ? b11 : b01, acc1, 0, 0, 0);
        }
#pragma unroll
        for (int j = 0; j < 4; ++j) v[j] = vn[j];
    }
    *(f32x4*)&Pr[w][0][lane][0] = acc0;
    *(f32x4*)&Pr[w][1][lane][0] = acc1;
    __syncthreads();
    split_reduce_store(Pr, tid, b, ms, nullptr, Tout, 1.f, 0.f);
}

// ---------------------------------------------------------------------------
// Passes 2..5: all-frag-layout streaming GEMM, fully contiguous loads,
// fused split-k reduce + T_k = a*(L@T_{k-1}) + c*T_{k-2} epilogue.
// grid 1024 blocks (b, ms) x 4 waves (s).
__global__ __launch_bounds__(256) void gemm_frag(const unsigned short* __restrict__ Lb,
                                                 const unsigned short* __restrict__ Tb,
                                                 const unsigned short* __restrict__ Tpp,
                                                 unsigned short* __restrict__ Tout,
                                                 float a, float c) {
    __shared__ __align__(16) float Pr[4][2][64][4];
    int tid = threadIdx.x, bid = blockIdx.x;
    int b = bid >> 8, ms = bid & 255;
    int s = tid >> 6, lane = tid & 63;
    const unsigned short* Ap = Lb + (((long)(b * 256 + ms) * 128 + s * 32) * 64 + lane) * 8;
    const unsigned short* Bp = Tb + tb_idx(b, s * 32, 0, lane);

    f32x4 acc0 = {0.f,0.f,0.f,0.f}, acc1 = {0.f,0.f,0.f,0.f};
    short8 Ar[4], B0r[4], B1r[4];
#pragma unroll
    for (int i = 0; i < 4; ++i) {
        Ar[i]  = *(const short8*)(Ap + (long)i * 512);
        B0r[i] = *(const short8*)(Bp + (long)i * 1024);
        B1r[i] = *(const short8*)(Bp + (long)i * 1024 + 512);
    }
#pragma unroll 4
    for (int ks = 0; ks < 32; ++ks) {
        int sl = ks & 3;
        short8 aa = Ar[sl], b0 = B0r[sl], b1 = B1r[sl];
        if (ks + 4 < 32) {
            Ar[sl]  = *(const short8*)(Ap + (long)(ks + 4) * 512);
            B0r[sl] = *(const short8*)(Bp + (long)(ks + 4) * 1024);
            B1r[sl] = *(const short8*)(Bp + (long)(ks + 4) * 1024 + 512);
        }
        acc0 = __builtin_amdgcn_mfma_f32_16x16x32_bf16(aa, b0, acc0, 0, 0, 0);
        acc1 = __builtin_amdgcn_mfma_f32_16x16x32_bf16(aa, b1, acc1, 0, 0, 0);
    }
    *(f32x4*)&Pr[s][0][lane][0] = acc0;
    *(f32x4*)&Pr[s][1][lane][0] = acc1;
    __syncthreads();
    split_reduce_store(Pr, tid, b, ms, Tpp, Tout, a, c);
}

// ---------------------------------------------------------------------------
// out[b][n][o] = sum_k sum_f T_k[b](f,n) * Wc[k][f][o]
// grid = B * 64 * 2(o-halves) = 512 blocks.
__global__ __launch_bounds__(256) void proj(const unsigned short* __restrict__ T, // K slots, Tb layout
                                            const unsigned short* __restrict__ Wc,
                                            float* __restrict__ out) {
    __shared__ __align__(16) unsigned short Tl[192][72];
    __shared__ __align__(16) unsigned short Wl[192][64];
    int tid = threadIdx.x, bid = blockIdx.x;
    int b = bid >> 7; int rem = bid & 127;
    int nc = rem >> 1; long n0 = (long)nc * 64; int oh = rem & 1;
    const long T_SLOT = (long)BB * FF * N4;
#pragma unroll
    for (int it = 0; it < 6; ++it) {
        int row = it * 32 + (tid >> 3);    // kf index
        int col = (tid & 7) * 8;           // n-local
        int k = row >> 5, f = row & 31;
        int ks = nc * 2 + (col >> 5), half = f >> 4;
        int lane = ((col & 31) >> 3) * 16 + (f & 15);
        *(i32x4*)&Tl[row][col] = *(const i32x4*)(T + (long)k * T_SLOT + tb_idx(b, ks, half, lane));
        *(i32x4*)&Wl[row][col] = *(const i32x4*)(Wc + (long)row * OO + oh * 64 + col);
    }
    __syncthreads();
    int ol = tid & 63;
    int nb = (tid >> 6) * 16;
    float acc[16];
#pragma unroll
    for (int r = 0; r < 16; ++r) acc[r] = 0.f;
    for (int kf = 0; kf < 192; ++kf) {
        float w = b2f(Wl[kf][ol]);
#pragma unroll
        for (int rv = 0; rv < 2; ++rv) {
            short8 tv = *(const short8*)&Tl[kf][nb + rv * 8];
#pragma unroll
            for (int e = 0; e < 8; ++e)
                acc[rv * 8 + e] += b2f((unsigned short)tv[e]) * w;
        }
    }
    int o = oh * 64 + ol;
#pragma unroll
    for (int r = 0; r < 16; ++r)
        out[((long)b * N4 + n0 + nb + r) * OO + o] = acc[r];
}

// ---------------------------------------------------------------------------
extern "C" void kernel_launch(void* const* d_in, const int* in_sizes, int n_in,
                              void* d_out, int out_size, void* d_ws, size_t ws_size,
                              hipStream_t stream) {
    const float* x     = (const float*)d_in[0];
    const float* L     = (const float*)d_in[1];
    const float* W     = (const float*)d_in[2];
    const float* theta = (const float*)d_in[3];
    float* out = (float*)d_out;
    char* ws = (char*)d_ws;

    const size_t LB_BYTES = (size_t)BB * N4 * N4 * 2;     // 128 MiB
    const size_t T_SLOT   = (size_t)BB * FF * N4;         // elems per slot
    const size_t T_BYTES  = (size_t)KK * T_SLOT * 2;      // 6 MiB

    unsigned short* Lb = (unsigned short*)ws;
    unsigned short* T  = (unsigned short*)(ws + LB_BYTES);
    unsigned short* Wc = (unsigned short*)(ws + LB_BYTES + T_BYTES);

    make_wc<<<96, 256, 0, stream>>>(W, theta, Wc);
    x_to_t<<<256, 256, 0, stream>>>(x, T);          // slot 0 = frag-layout bf16(x^T)

    // pass 1: T1 = L @ T0, fused f32->frag transcode of L, in-block split-k reduce
    gemm_pass1<<<1024, 256, 0, stream>>>(L, Lb, T, T + 1 * T_SLOT);

    // passes 2..5: T_k = 2 L @ T_{k-1} - T_{k-2}, fused reduce+update epilogue
    for (int k = 2; k < KK; ++k) {
        gemm_frag<<<1024, 256, 0, stream>>>(Lb, T + (k - 1) * T_SLOT,
                                            T + (k - 2) * T_SLOT, T + k * T_SLOT,
                                            2.f, -1.f);
    }

    proj<<<512, 256, 0, stream>>>(T, Wc, out);
}

// Round 3
// 507.873 us; speedup vs baseline: 1.0535x; 1.0089x over previous
//
#include <hip/hip_runtime.h>

// Problem constants
#define N4 4096
#define FF 32
#define KK 6
#define OO 128
#define BB 4

typedef __attribute__((ext_vector_type(8))) short  short8;   // 8 bf16 MFMA A/B frag
typedef __attribute__((ext_vector_type(4))) float  f32x4;
typedef __attribute__((ext_vector_type(4))) int    i32x4;
typedef __attribute__((ext_vector_type(2))) unsigned int u32x2;

__device__ __forceinline__ float b2f(unsigned short h) {
    union { float f; unsigned u; } v; v.u = ((unsigned)h) << 16; return v.f;
}
__device__ __forceinline__ unsigned short f2b(float f) {
    union { float f; unsigned u; } v; v.f = f;
    unsigned r = (v.u + 0x7FFFu + ((v.u >> 16) & 1u)) >> 16;
    return (unsigned short)r;
}

// Tb frag layout: element (f, n) of T lives at
//   tb_idx(b, ks=n>>5, half=f>>4, lane=((n>>3)&3)*16 + (f&15)) + (n&7)
__device__ __forceinline__ long tb_idx(int b, int ks, int half, int lane) {
    return ((((long)b * 128 + ks) * 2 + half) * 64 + lane) * 8;
}

// ---------------------------------------------------------------------------
// Wc[k][f][o] = bf16(theta[k] * W[k][f][o])
__global__ __launch_bounds__(256) void make_wc(const float* __restrict__ W,
                                               const float* __restrict__ theta,
                                               unsigned short* __restrict__ Wc) {
    int idx = blockIdx.x * 256 + threadIdx.x;
    int k = idx >> 12;
    Wc[idx] = f2b(theta[k] * W[idx]);
}

// ---------------------------------------------------------------------------
// x [B][N][F] f32 -> T0 in Tb frag layout.  grid B*64=256 blocks (b, nc).
__global__ __launch_bounds__(256) void x_to_t(const float* __restrict__ x,
                                              unsigned short* __restrict__ T0) {
    __shared__ __align__(16) unsigned short Ol[32][72];   // [f][n-local]
    int tid = threadIdx.x, bid = blockIdx.x;
    int b = bid >> 6; int nc = bid & 63; long n0 = (long)nc * 64;
    int nl = tid >> 2, fg = (tid & 3) * 8;
    const float* src = x + ((long)b * N4 + n0 + nl) * FF + fg;
    f32x4 v0 = *(const f32x4*)src;
    f32x4 v1 = *(const f32x4*)(src + 4);
#pragma unroll
    for (int e = 0; e < 4; ++e) {
        Ol[fg + e][nl]     = f2b(v0[e]);
        Ol[fg + 4 + e][nl] = f2b(v1[e]);
    }
    __syncthreads();
    int ks_l = tid >> 7, half = (tid >> 6) & 1, lane = tid & 63;
    int quad = lane >> 4, l16 = lane & 15;
    int f = half * 16 + l16, nloc = ks_l * 32 + quad * 8;
    *(i32x4*)(T0 + tb_idx(b, nc * 2 + ks_l, half, lane)) = *(const i32x4*)&Ol[f][nloc];
}

// ---------------------------------------------------------------------------
// Fused split-k(4) reduce + Chebyshev update + Tb-layout store (pass 1 only).
__device__ __forceinline__ void split_reduce_store(const float (*Pr)[2][64][4],
                                                   int tid, int b, int ms,
                                                   const unsigned short* __restrict__ Tpp,
                                                   unsigned short* __restrict__ Tout,
                                                   float a, float c) {
    if (tid >= 64) return;
    int half = tid >> 5, qi = (tid >> 4) & 1, l16 = tid & 15;
    f32x4 sA = {0.f, 0.f, 0.f, 0.f}, sB = {0.f, 0.f, 0.f, 0.f};
#pragma unroll
    for (int ss = 0; ss < 4; ++ss) {
        f32x4 va = *(const f32x4*)&Pr[ss][half][qi * 32 + l16][0];
        f32x4 vb = *(const f32x4*)&Pr[ss][half][qi * 32 + 16 + l16][0];
#pragma unroll
        for (int e = 0; e < 4; ++e) { sA[e] += va[e]; sB[e] += vb[e]; }
    }
    float vals[8] = {sA[0], sA[1], sA[2], sA[3], sB[0], sB[1], sB[2], sB[3]};
    int lane_o = ((ms & 1) * 2 + qi) * 16 + l16;
    long oidx = tb_idx(b, ms >> 1, half, lane_o);
    i32x4 pk;
    if (Tpp) {
        short8 tv = *(const short8*)(Tpp + oidx);
#pragma unroll
        for (int p = 0; p < 4; ++p)
            pk[p] = (unsigned)f2b(a * vals[2 * p]     + c * b2f((unsigned short)tv[2 * p]))
                  | ((unsigned)f2b(a * vals[2 * p + 1] + c * b2f((unsigned short)tv[2 * p + 1])) << 16);
    } else {
#pragma unroll
        for (int p = 0; p < 4; ++p)
            pk[p] = (unsigned)f2b(a * vals[2 * p])
                  | ((unsigned)f2b(a * vals[2 * p + 1]) << 16);
    }
    *(i32x4*)(Tout + oidx) = pk;
}

// ---------------------------------------------------------------------------
// Pass 1 fused: reads f32 L (coalesced 256B/row chunks), wave-local LDS permute
// to frag layout, writes Lb (wave-contiguous 1KB), computes T1 = L @ T0, and
// reduces split-k in-block -> writes T1 directly.
// grid 1024 blocks (b, ms) x 4 waves (w = split-k quarter).
__global__ __launch_bounds__(256) void gemm_pass1(const float* __restrict__ L,
                                                  unsigned short* __restrict__ Lb,
                                                  const unsigned short* __restrict__ Tb0,
                                                  unsigned short* __restrict__ Tout) {
    __shared__ __align__(16) unsigned short Sw[4][2][2][64][8];  // [wave][buf][ks_loc][lane][e]
    __shared__ __align__(16) float Pr[4][2][64][4];              // split-k partials
    int tid = threadIdx.x, bid = blockIdx.x;
    int b = bid >> 8, ms = bid & 255;
    int w = tid >> 6, lane = tid & 63, l16 = lane & 15;
    int rgrp = lane >> 4;                       // row group for reads
    const float* Ls = L + ((long)b * N4 + ms * 16 + rgrp) * N4 + (long)w * 1024 + l16 * 4;
    int ks_loc_w = l16 >> 3, quad_w = (l16 >> 1) & 3, e0 = (l16 & 1) * 4;
    const unsigned short* Bbase = Tb0 + tb_idx(b, w * 32, 0, lane);
    unsigned short* LbBase = Lb + (((long)(b * 256 + ms) * 128 + w * 32) * 64 + lane) * 8;

    f32x4 acc0 = {0.f,0.f,0.f,0.f}, acc1 = {0.f,0.f,0.f,0.f};
    f32x4 v[4], vn[4];
#pragma unroll
    for (int j = 0; j < 4; ++j) v[j] = *(const f32x4*)(Ls + (long)j * 4 * N4);

    for (int it = 0; it < 16; ++it) {
        if (it + 1 < 16) {
#pragma unroll
            for (int j = 0; j < 4; ++j)
                vn[j] = *(const f32x4*)(Ls + (long)j * 4 * N4 + (it + 1) * 64);
        }
        short8 b00 = *(const short8*)(Bbase + (long)(it * 2 + 0) * 1024);
        short8 b01 = *(const short8*)(Bbase + (long)(it * 2 + 0) * 1024 + 512);
        short8 b10 = *(const short8*)(Bbase + (long)(it * 2 + 1) * 1024);
        short8 b11 = *(const short8*)(Bbase + (long)(it * 2 + 1) * 1024 + 512);
        unsigned short* Sb = &Sw[w][it & 1][0][0][0];
#pragma unroll
        for (int j = 0; j < 4; ++j) {
            u32x2 pk;
            pk[0] = (unsigned)f2b(v[j][0]) | ((unsigned)f2b(v[j][1]) << 16);
            pk[1] = (unsigned)f2b(v[j][2]) | ((unsigned)f2b(v[j][3]) << 16);
            int lane_o = quad_w * 16 + j * 4 + rgrp;
            *(u32x2*)(Sb + (ks_loc_w * 64 + lane_o) * 8 + e0) = pk;
        }
#pragma unroll
        for (int h = 0; h < 2; ++h) {
            short8 af = *(const short8*)(Sb + (h * 64 + lane) * 8);
            *(short8*)(LbBase + (long)(it * 2 + h) * 512) = af;  // 1KB wave-contiguous
            acc0 = __builtin_amdgcn_mfma_f32_16x16x32_bf16(af, h ? b10 : b00, acc0, 0, 0, 0);
            acc1 = __builtin_amdgcn_mfma_f32_16x16x32_bf16(af, h ? b11 : b01, acc1, 0, 0, 0);
        }
#pragma unroll
        for (int j = 0; j < 4; ++j) v[j] = vn[j];
    }
    *(f32x4*)&Pr[w][0][lane][0] = acc0;
    *(f32x4*)&Pr[w][1][lane][0] = acc1;
    __syncthreads();
    split_reduce_store(Pr, tid, b, ms, nullptr, Tout, 1.f, 0.f);
}

// ---------------------------------------------------------------------------
// Passes 2..5: M=32 per block (2 row-groups), split-k over 8 waves,
// 512 threads, grid 512 (b x 128 m-tiles).  Each B-frag pair feeds 4 MFMAs
// (2x the reuse of the old M=16 version) -> B-side cache traffic halves.
// Fused split-k reduce + T_k = a*(L@T_{k-1}) + c*T_{k-2} epilogue.
__global__ __launch_bounds__(512) void gemm_frag(const unsigned short* __restrict__ Lb,
                                                 const unsigned short* __restrict__ Tb,
                                                 const unsigned short* __restrict__ Tpp,
                                                 unsigned short* __restrict__ Tout,
                                                 float a, float c) {
    __shared__ __align__(16) float Pr[8][2][2][64][4];   // [wave][g][h][lane][4] = 16 KB
    int tid = threadIdx.x;
    int bid = blockIdx.x;
    bid = (bid & 7) * 64 + (bid >> 3);        // XCD-chunk swizzle, bijective (512 = 8*64)
    int b = bid >> 7, m32 = bid & 127;
    int s = tid >> 6, lane = tid & 63;

    const unsigned short* Ap0 = Lb + (((long)(b * 256 + m32 * 2 + 0) * 128 + s * 16) * 64 + lane) * 8;
    const unsigned short* Ap1 = Lb + (((long)(b * 256 + m32 * 2 + 1) * 128 + s * 16) * 64 + lane) * 8;
    const unsigned short* Bp  = Tb + tb_idx(b, s * 16, 0, lane);

    f32x4 acc00 = {0.f,0.f,0.f,0.f}, acc01 = {0.f,0.f,0.f,0.f};
    f32x4 acc10 = {0.f,0.f,0.f,0.f}, acc11 = {0.f,0.f,0.f,0.f};
    short8 A0r[4], A1r[4], B0r[4], B1r[4];
#pragma unroll
    for (int i = 0; i < 4; ++i) {
        A0r[i] = *(const short8*)(Ap0 + (long)i * 512);
        A1r[i] = *(const short8*)(Ap1 + (long)i * 512);
        B0r[i] = *(const short8*)(Bp + (long)i * 1024);
        B1r[i] = *(const short8*)(Bp + (long)i * 1024 + 512);
    }
#pragma unroll
    for (int i = 0; i < 16; ++i) {
        int sl = i & 3;
        short8 a0 = A0r[sl], a1 = A1r[sl], b0 = B0r[sl], b1 = B1r[sl];
        if (i + 4 < 16) {
            A0r[sl] = *(const short8*)(Ap0 + (long)(i + 4) * 512);
            A1r[sl] = *(const short8*)(Ap1 + (long)(i + 4) * 512);
            B0r[sl] = *(const short8*)(Bp + (long)(i + 4) * 1024);
            B1r[sl] = *(const short8*)(Bp + (long)(i + 4) * 1024 + 512);
        }
        acc00 = __builtin_amdgcn_mfma_f32_16x16x32_bf16(a0, b0, acc00, 0, 0, 0);
        acc01 = __builtin_amdgcn_mfma_f32_16x16x32_bf16(a0, b1, acc01, 0, 0, 0);
        acc10 = __builtin_amdgcn_mfma_f32_16x16x32_bf16(a1, b0, acc10, 0, 0, 0);
        acc11 = __builtin_amdgcn_mfma_f32_16x16x32_bf16(a1, b1, acc11, 0, 0, 0);
    }
    *(f32x4*)&Pr[s][0][0][lane][0] = acc00;
    *(f32x4*)&Pr[s][0][1][lane][0] = acc01;
    *(f32x4*)&Pr[s][1][0][lane][0] = acc10;
    *(f32x4*)&Pr[s][1][1][lane][0] = acc11;
    __syncthreads();
    if (tid >= 128) return;
    // reduce: strip g = tid>>6 (rows m32*32 + g*16 .. +15)
    int g = tid >> 6, t = tid & 63;
    int half = t >> 5, qi = (t >> 4) & 1, l16 = t & 15;
    f32x4 sA = {0.f,0.f,0.f,0.f}, sB = {0.f,0.f,0.f,0.f};
#pragma unroll
    for (int ss = 0; ss < 8; ++ss) {
        f32x4 va = *(const f32x4*)&Pr[ss][g][half][qi * 32 + l16][0];
        f32x4 vb = *(const f32x4*)&Pr[ss][g][half][qi * 32 + 16 + l16][0];
#pragma unroll
        for (int e = 0; e < 4; ++e) { sA[e] += va[e]; sB[e] += vb[e]; }
    }
    float vals[8] = {sA[0], sA[1], sA[2], sA[3], sB[0], sB[1], sB[2], sB[3]};
    int lane_o = (g * 2 + qi) * 16 + l16;
    long oidx = tb_idx(b, m32, half, lane_o);
    short8 tv = *(const short8*)(Tpp + oidx);
    i32x4 pk;
#pragma unroll
    for (int p = 0; p < 4; ++p)
        pk[p] = (unsigned)f2b(a * vals[2 * p]     + c * b2f((unsigned short)tv[2 * p]))
              | ((unsigned)f2b(a * vals[2 * p + 1] + c * b2f((unsigned short)tv[2 * p + 1])) << 16);
    *(i32x4*)(Tout + oidx) = pk;
}

// ---------------------------------------------------------------------------
// out[b][n][o] = sum_k sum_f T_k[b](f,n) * Wc[k][f][o]
// grid = B * 64 * 2(o-halves) = 512 blocks.
__global__ __launch_bounds__(256) void proj(const unsigned short* __restrict__ T, // K slots, Tb layout
                                            const unsigned short* __restrict__ Wc,
                                            float* __restrict__ out) {
    __shared__ __align__(16) unsigned short Tl[192][72];
    __shared__ __align__(16) unsigned short Wl[192][64];
    int tid = threadIdx.x, bid = blockIdx.x;
    int b = bid >> 7; int rem = bid & 127;
    int nc = rem >> 1; long n0 = (long)nc * 64; int oh = rem & 1;
    const long T_SLOT = (long)BB * FF * N4;
#pragma unroll
    for (int it = 0; it < 6; ++it) {
        int row = it * 32 + (tid >> 3);    // kf index
        int col = (tid & 7) * 8;           // n-local
        int k = row >> 5, f = row & 31;
        int ks = nc * 2 + (col >> 5), half = f >> 4;
        int lane = ((col & 31) >> 3) * 16 + (f & 15);
        *(i32x4*)&Tl[row][col] = *(const i32x4*)(T + (long)k * T_SLOT + tb_idx(b, ks, half, lane));
        *(i32x4*)&Wl[row][col] = *(const i32x4*)(Wc + (long)row * OO + oh * 64 + col);
    }
    __syncthreads();
    int ol = tid & 63;
    int nb = (tid >> 6) * 16;
    float acc[16];
#pragma unroll
    for (int r = 0; r < 16; ++r) acc[r] = 0.f;
    for (int kf = 0; kf < 192; ++kf) {
        float w = b2f(Wl[kf][ol]);
#pragma unroll
        for (int rv = 0; rv < 2; ++rv) {
            short8 tv = *(const short8*)&Tl[kf][nb + rv * 8];
#pragma unroll
            for (int e = 0; e < 8; ++e)
                acc[rv * 8 + e] += b2f((unsigned short)tv[e]) * w;
        }
    }
    int o = oh * 64 + ol;
#pragma unroll
    for (int r = 0; r < 16; ++r)
        out[((long)b * N4 + n0 + nb + r) * OO + o] = acc[r];
}

// ---------------------------------------------------------------------------
extern "C" void kernel_launch(void* const* d_in, const int* in_sizes, int n_in,
                              void* d_out, int out_size, void* d_ws, size_t ws_size,
                              hipStream_t stream) {
    const float* x     = (const float*)d_in[0];
    const float* L     = (const float*)d_in[1];
    const float* W     = (const float*)d_in[2];
    const float* theta = (const float*)d_in[3];
    float* out = (float*)d_out;
    char* ws = (char*)d_ws;

    const size_t LB_BYTES = (size_t)BB * N4 * N4 * 2;     // 128 MiB
    const size_t T_SLOT   = (size_t)BB * FF * N4;         // elems per slot
    const size_t T_BYTES  = (size_t)KK * T_SLOT * 2;      // 6 MiB

    unsigned short* Lb = (unsigned short*)ws;
    unsigned short* T  = (unsigned short*)(ws + LB_BYTES);
    unsigned short* Wc = (unsigned short*)(ws + LB_BYTES + T_BYTES);

    make_wc<<<96, 256, 0, stream>>>(W, theta, Wc);
    x_to_t<<<256, 256, 0, stream>>>(x, T);          // slot 0 = frag-layout bf16(x^T)

    // pass 1: T1 = L @ T0, fused f32->frag transcode of L, in-block split-k reduce
    gemm_pass1<<<1024, 256, 0, stream>>>(L, Lb, T, T + 1 * T_SLOT);

    // passes 2..5: T_k = 2 L @ T_{k-1} - T_{k-2}, M=32 blocks, split-k(8)
    for (int k = 2; k < KK; ++k) {
        gemm_frag<<<512, 512, 0, stream>>>(Lb, T + (k - 1) * T_SLOT,
                                           T + (k - 2) * T_SLOT, T + k * T_SLOT,
                                           2.f, -1.f);
    }

    proj<<<512, 256, 0, stream>>>(T, Wc, out);
}